// Round 1
// baseline (946.866 us; speedup 1.0000x reference)
//
#include <hip/hip_runtime.h>
#include <stdint.h>

// ---------------------------------------------------------------------------
// 2-layer GCN: relu(gcn(x,W1,b1)) -> batchnorm -> relu(gcn(.,W2,b2))
// n=100000, E=1.6M, f_in=25, hid=128, all fp32.
// Strategy: build CSR (by target) per launch, gather-based propagation
// (no float atomics), BN fused into GEMM2 input load, d_out reused as the
// intermediate activation buffer.
// ---------------------------------------------------------------------------

#define HID 128

// --- detect whether edge_index buffer is int64 or int32 --------------------
// int64 little-endian values < 2^31: every odd 32-bit word is 0.
__global__ void detect_kernel(const unsigned int* __restrict__ w, int* __restrict__ mode, int nwords) {
    __shared__ int any;
    if (threadIdx.x == 0) any = 0;
    __syncthreads();
    for (int i = threadIdx.x * 2 + 1; i < nwords && i < 8192; i += 512) {
        if (w[i] != 0) atomicOr(&any, 1);
    }
    __syncthreads();
    if (threadIdx.x == 0) *mode = any ? 0 : 1;  // 1 => int64 layout
}

__device__ __forceinline__ int load_idx(const void* ei, size_t i, int mode) {
    return mode ? (int)((const long long*)ei)[i] : ((const int*)ei)[i];
}

// --- in-degree histogram (targets = col) -----------------------------------
__global__ void count_kernel(const void* __restrict__ ei, const int* __restrict__ modep,
                             int* __restrict__ cnt, int E) {
    int e = blockIdx.x * blockDim.x + threadIdx.x;
    if (e >= E) return;
    int mode = *modep;
    int c = load_idx(ei, (size_t)E + e, mode);
    atomicAdd(&cnt[c], 1);
}

// --- exclusive scan over cnt -> rowptr/cursor, plus dinv = rsqrt(deg+1) ----
__global__ __launch_bounds__(1024) void scan_kernel(const int* __restrict__ cnt,
                                                    int* __restrict__ rowptr,
                                                    int* __restrict__ cursor,
                                                    float* __restrict__ dinv, int n) {
    __shared__ int s[1024];
    int t = threadIdx.x;
    int chunk = (n + 1023) >> 10;
    int beg = t * chunk;
    int end = beg + chunk; if (end > n) end = n;
    int local = 0;
    for (int i = beg; i < end; ++i) local += cnt[i];
    s[t] = local;
    __syncthreads();
    for (int off = 1; off < 1024; off <<= 1) {
        int v = s[t] + ((t >= off) ? s[t - off] : 0);
        __syncthreads();
        s[t] = v;
        __syncthreads();
    }
    int running = s[t] - local;  // exclusive prefix
    for (int i = beg; i < end; ++i) {
        rowptr[i] = running;
        cursor[i] = running;
        int c = cnt[i];
        dinv[i] = rsqrtf((float)(c + 1));  // +1 self loop; always > 0
        running += c;
    }
    if (t == 1023) rowptr[n] = s[1023];
}

// --- scatter edges into CSR slots ------------------------------------------
__global__ void scatter_kernel(const void* __restrict__ ei, const int* __restrict__ modep,
                               int* __restrict__ cursor, int* __restrict__ edge_src, int E) {
    int e = blockIdx.x * blockDim.x + threadIdx.x;
    if (e >= E) return;
    int mode = *modep;
    int r = load_idx(ei, (size_t)e, mode);
    int c = load_idx(ei, (size_t)E + e, mode);
    int pos = atomicAdd(&cursor[c], 1);
    edge_src[pos] = r;
}

// --- GEMM1: h = x @ W1   (K=25, W1 staged in LDS) --------------------------
__global__ __launch_bounds__(256) void gemm1_kernel(const float* __restrict__ x,
                                                    const float* __restrict__ W,
                                                    float* __restrict__ h, int n) {
    __shared__ float lw[25 * HID];
    for (int i = threadIdx.x; i < 25 * HID; i += 256) lw[i] = W[i];
    __syncthreads();
    int g = threadIdx.x >> 7, c = threadIdx.x & 127;
    for (int r = blockIdx.x * 2 + g; r < n; r += gridDim.x * 2) {
        const float* xr = x + (size_t)r * 25;
        float acc = 0.f;
        #pragma unroll
        for (int k = 0; k < 25; ++k) acc = fmaf(xr[k], lw[k * HID + c], acc);
        h[(size_t)r * HID + c] = acc;
    }
}

// --- propagation: out[c] = relu(dinv[c]*(sum_e h[src]*dinv[src] + h[c]*dinv[c]) + b)
// one wave per target node; lane owns 2 features (float2).
__global__ __launch_bounds__(256) void propagate_kernel(
    const float* __restrict__ h, const int* __restrict__ rowptr,
    const int* __restrict__ edge_src, const float* __restrict__ dinv,
    const float* __restrict__ bias, float* __restrict__ out, int n) {
    int wid = (blockIdx.x * 256 + threadIdx.x) >> 6;
    if (wid >= n) return;
    int lane = threadIdx.x & 63;
    int beg = rowptr[wid], end = rowptr[wid + 1];
    float dc = dinv[wid];
    float ax = 0.f, ay = 0.f;
    for (int b = beg; b < end; b += 64) {
        int m = end - b; if (m > 64) m = 64;
        int s = 0; float w = 0.f;
        if (lane < m) { s = edge_src[b + lane]; w = dinv[s]; }
        for (int j = 0; j < m; ++j) {
            int sj = __shfl(s, j);
            float wj = __shfl(w, j);
            float2 v = *(const float2*)(h + (size_t)sj * HID + lane * 2);
            ax = fmaf(v.x, wj, ax);
            ay = fmaf(v.y, wj, ay);
        }
    }
    {   // self loop
        float2 v = *(const float2*)(h + (size_t)wid * HID + lane * 2);
        ax = fmaf(v.x, dc, ax);
        ay = fmaf(v.y, dc, ay);
    }
    float bx = bias[lane * 2], by = bias[lane * 2 + 1];
    ax = fmaxf(fmaf(ax, dc, bx), 0.f);
    ay = fmaxf(fmaf(ay, dc, by), 0.f);
    *(float2*)(out + (size_t)wid * HID + lane * 2) = make_float2(ax, ay);
}

// --- BN stats: per-channel sum and sumsq -----------------------------------
__global__ __launch_bounds__(256) void bn_stats_kernel(const float* __restrict__ y,
                                                       float* __restrict__ sum,
                                                       float* __restrict__ sumsq, int n) {
    int c = threadIdx.x & 127;
    int g = threadIdx.x >> 7;
    float s = 0.f, s2 = 0.f;
    for (int r = blockIdx.x * 2 + g; r < n; r += gridDim.x * 2) {
        float v = y[(size_t)r * HID + c];
        s += v;
        s2 = fmaf(v, v, s2);
    }
    __shared__ float ls[256], ls2[256];
    ls[threadIdx.x] = s; ls2[threadIdx.x] = s2;
    __syncthreads();
    if (threadIdx.x < 128) {
        atomicAdd(&sum[c], ls[threadIdx.x] + ls[threadIdx.x + 128]);
        atomicAdd(&sumsq[c], ls2[threadIdx.x] + ls2[threadIdx.x + 128]);
    }
}

__global__ void bn_finalize_kernel(const float* __restrict__ sum, const float* __restrict__ sumsq,
                                   const float* __restrict__ gamma, const float* __restrict__ beta,
                                   float* __restrict__ scale, float* __restrict__ shift, float inv_n) {
    int c = threadIdx.x;
    float mean = sum[c] * inv_n;
    float var = sumsq[c] * inv_n - mean * mean;
    float sc = gamma[c] * rsqrtf(var + 1e-5f);
    scale[c] = sc;
    shift[c] = beta[c] - mean * sc;
}

// --- GEMM2: h2 = bn(y1) @ W2  (K=128), BN fused into tile load -------------
// 64-row x 128-col tile, K-chunks of 32; per-thread 8x4 register tile.
__global__ __launch_bounds__(256) void gemm2_kernel(
    const float* __restrict__ y, const float* __restrict__ W,
    const float* __restrict__ scale, const float* __restrict__ shift,
    float* __restrict__ out, int n) {
    __shared__ float lw[32][HID];   // [k][c]
    __shared__ float ly[32][68];    // [k][r] (64 rows + pad; 68*4 is 16B-aligned)
    int t = threadIdx.x;
    int base = blockIdx.x * 64;
    int c4 = (t & 31) * 4;
    int rg = t >> 5;  // 0..7
    float acc[8][4];
    #pragma unroll
    for (int r = 0; r < 8; ++r)
        #pragma unroll
        for (int c = 0; c < 4; ++c) acc[r][c] = 0.f;
    for (int kc = 0; kc < 4; ++kc) {
        #pragma unroll
        for (int i = 0; i < 16; ++i) {
            int idx = t + i * 256;
            int kk = idx >> 7, cc = idx & 127;
            lw[kk][cc] = W[(size_t)(kc * 32 + kk) * HID + cc];
        }
        #pragma unroll
        for (int i = 0; i < 8; ++i) {
            int idx = t + i * 256;
            int k = idx & 31, r = idx >> 5;
            int gr = base + r;
            int gk = kc * 32 + k;
            float v = 0.f;
            if (gr < n) v = fmaf(y[(size_t)gr * HID + gk], scale[gk], shift[gk]);
            ly[k][r] = v;
        }
        __syncthreads();
        #pragma unroll
        for (int k = 0; k < 32; ++k) {
            float4 wv = *(const float4*)&lw[k][c4];
            float4 y0 = *(const float4*)&ly[k][rg * 8];
            float4 y1 = *(const float4*)&ly[k][rg * 8 + 4];
            float yv[8] = {y0.x, y0.y, y0.z, y0.w, y1.x, y1.y, y1.z, y1.w};
            #pragma unroll
            for (int r = 0; r < 8; ++r) {
                acc[r][0] = fmaf(yv[r], wv.x, acc[r][0]);
                acc[r][1] = fmaf(yv[r], wv.y, acc[r][1]);
                acc[r][2] = fmaf(yv[r], wv.z, acc[r][2]);
                acc[r][3] = fmaf(yv[r], wv.w, acc[r][3]);
            }
        }
        __syncthreads();
    }
    #pragma unroll
    for (int r = 0; r < 8; ++r) {
        int gr = base + rg * 8 + r;
        if (gr < n)
            *(float4*)&out[(size_t)gr * HID + c4] =
                make_float4(acc[r][0], acc[r][1], acc[r][2], acc[r][3]);
    }
}

extern "C" void kernel_launch(void* const* d_in, const int* in_sizes, int n_in,
                              void* d_out, int out_size, void* d_ws, size_t ws_size,
                              hipStream_t stream) {
    const float* x     = (const float*)d_in[0];
    const void*  ei    = d_in[1];
    const float* W1    = (const float*)d_in[2];
    const float* b1    = (const float*)d_in[3];
    const float* gamma = (const float*)d_in[4];
    const float* beta  = (const float*)d_in[5];
    const float* W2    = (const float*)d_in[6];
    const float* b2    = (const float*)d_in[7];
    float* out = (float*)d_out;

    const int f_in = 25;
    int n = in_sizes[0] / f_in;
    int E = in_sizes[1] / 2;

    char* ws = (char*)d_ws;
    size_t off = 0;
    auto alloc = [&](size_t bytes) -> void* {
        void* p = ws + off;
        off += (bytes + 511) & ~(size_t)511;
        return p;
    };
    int*   cnt      = (int*)alloc((size_t)n * 4);
    int*   rowptr   = (int*)alloc(((size_t)n + 1) * 4);
    int*   cursor   = (int*)alloc((size_t)n * 4);
    float* dinv     = (float*)alloc((size_t)n * 4);
    int*   edge_src = (int*)alloc((size_t)E * 4);
    float* bnacc    = (float*)alloc(256 * 4);   // sum[128] ++ sumsq[128]
    float* sclshift = (float*)alloc(256 * 4);   // scale[128] ++ shift[128]
    int*   mode     = (int*)alloc(4);
    float* h        = (float*)alloc((size_t)n * HID * 4);  // h1, then h2

    hipMemsetAsync(cnt, 0, (size_t)n * 4, stream);
    hipMemsetAsync(bnacc, 0, 256 * 4, stream);

    detect_kernel<<<1, 256, 0, stream>>>((const unsigned int*)ei, mode, 2 * E);
    count_kernel<<<(E + 255) / 256, 256, 0, stream>>>(ei, mode, cnt, E);
    scan_kernel<<<1, 1024, 0, stream>>>(cnt, rowptr, cursor, dinv, n);
    scatter_kernel<<<(E + 255) / 256, 256, 0, stream>>>(ei, mode, cursor, edge_src, E);

    // layer 1: h1 = x@W1 ; y1 = relu(prop(h1) + b1) -> stored in d_out
    gemm1_kernel<<<4096, 256, 0, stream>>>(x, W1, h, n);
    propagate_kernel<<<(n + 3) / 4, 256, 0, stream>>>(h, rowptr, edge_src, dinv, b1, out, n);

    // batchnorm stats on y1
    bn_stats_kernel<<<512, 256, 0, stream>>>(out, bnacc, bnacc + 128, n);
    bn_finalize_kernel<<<1, 128, 0, stream>>>(bnacc, bnacc + 128, gamma, beta,
                                              sclshift, sclshift + 128, 1.0f / (float)n);

    // layer 2: h2 = bn(y1)@W2 (into h buffer) ; out = relu(prop(h2) + b2)
    gemm2_kernel<<<(n + 63) / 64, 256, 0, stream>>>(out, W2, sclshift, sclshift + 128, h, n);
    propagate_kernel<<<(n + 3) / 4, 256, 0, stream>>>(h, rowptr, edge_src, dinv, b2, out, n);
}

// Round 5
// 680.870 us; speedup vs baseline: 1.3907x; 1.3907x over previous
//
#include <hip/hip_runtime.h>
#include <stdint.h>

// ---------------------------------------------------------------------------
// 2-layer GCN: relu(gcn(x,W1,b1)) -> batchnorm -> relu(gcn(.,W2,b2))
// n=100000, E=1.6M, f_in=25, hid=128, all fp32.
// R2: replaced the single-block serial scan (280us, 30% of runtime, 0.14%
// occupancy) with a 3-phase parallel scan (~15us predicted).
// R3/R4/R5: resubmits — benches died on an unresponsive container (infra;
// same pod 'dear-ok-senior-royal' each time, kernel never executed).
// ---------------------------------------------------------------------------

#define HID 128
#define SCAN_CHUNK 1024   // elements per block in the parallel scan

// --- detect whether edge_index buffer is int64 or int32 --------------------
// int64 little-endian values < 2^31: every odd 32-bit word is 0.
__global__ void detect_kernel(const unsigned int* __restrict__ w, int* __restrict__ mode, int nwords) {
    __shared__ int any;
    if (threadIdx.x == 0) any = 0;
    __syncthreads();
    for (int i = threadIdx.x * 2 + 1; i < nwords && i < 8192; i += 512) {
        if (w[i] != 0) atomicOr(&any, 1);
    }
    __syncthreads();
    if (threadIdx.x == 0) *mode = any ? 0 : 1;  // 1 => int64 layout
}

__device__ __forceinline__ int load_idx(const void* ei, size_t i, int mode) {
    return mode ? (int)((const long long*)ei)[i] : ((const int*)ei)[i];
}

// --- in-degree histogram (targets = col) -----------------------------------
__global__ void count_kernel(const void* __restrict__ ei, const int* __restrict__ modep,
                             int* __restrict__ cnt, int E) {
    int e = blockIdx.x * blockDim.x + threadIdx.x;
    if (e >= E) return;
    int mode = *modep;
    int c = load_idx(ei, (size_t)E + e, mode);
    atomicAdd(&cnt[c], 1);
}

// --- parallel scan phase 1: per-block sums ---------------------------------
__global__ __launch_bounds__(256) void scan_partial_kernel(const int* __restrict__ cnt,
                                                           int* __restrict__ blocksum, int n) {
    int i = blockIdx.x * SCAN_CHUNK + threadIdx.x * 4;
    int4 v = make_int4(0, 0, 0, 0);
    if (i + 3 < n) v = *(const int4*)(cnt + i);
    else {
        if (i + 0 < n) v.x = cnt[i + 0];
        if (i + 1 < n) v.y = cnt[i + 1];
        if (i + 2 < n) v.z = cnt[i + 2];
    }
    int s = v.x + v.y + v.z + v.w;
    #pragma unroll
    for (int off = 32; off > 0; off >>= 1) s += __shfl_down(s, off);
    __shared__ int ls[4];
    if ((threadIdx.x & 63) == 0) ls[threadIdx.x >> 6] = s;
    __syncthreads();
    if (threadIdx.x == 0) blocksum[blockIdx.x] = ls[0] + ls[1] + ls[2] + ls[3];
}

// --- parallel scan phase 2: scan block sums (nb <= 1024) -------------------
__global__ __launch_bounds__(1024) void scan_blocksums_kernel(const int* __restrict__ blocksum,
                                                              int* __restrict__ blockoff,
                                                              int* __restrict__ rowptr,
                                                              int nb, int n) {
    __shared__ int s[1024];
    int t = threadIdx.x;
    int own = (t < nb) ? blocksum[t] : 0;
    s[t] = own;
    __syncthreads();
    for (int off = 1; off < 1024; off <<= 1) {
        int v = s[t] + ((t >= off) ? s[t - off] : 0);
        __syncthreads();
        s[t] = v;
        __syncthreads();
    }
    if (t < nb) blockoff[t] = s[t] - own;  // exclusive
    if (t == 1023) rowptr[n] = s[1023];    // total
}

// --- parallel scan phase 3: per-element exclusive prefix + dinv ------------
__global__ __launch_bounds__(256) void scan_finalize_kernel(const int* __restrict__ cnt,
                                                            const int* __restrict__ blockoff,
                                                            int* __restrict__ rowptr,
                                                            int* __restrict__ cursor,
                                                            float* __restrict__ dinv, int n) {
    int t = threadIdx.x;
    int i = blockIdx.x * SCAN_CHUNK + t * 4;
    int4 v = make_int4(0, 0, 0, 0);
    if (i + 3 < n) v = *(const int4*)(cnt + i);
    else {
        if (i + 0 < n) v.x = cnt[i + 0];
        if (i + 1 < n) v.y = cnt[i + 1];
        if (i + 2 < n) v.z = cnt[i + 2];
    }
    int own = v.x + v.y + v.z + v.w;
    __shared__ int s[256];
    s[t] = own;
    __syncthreads();
    for (int off = 1; off < 256; off <<= 1) {
        int x = s[t] + ((t >= off) ? s[t - off] : 0);
        __syncthreads();
        s[t] = x;
        __syncthreads();
    }
    int e0 = blockoff[blockIdx.x] + s[t] - own;  // exclusive prefix of element i
    int e1 = e0 + v.x, e2 = e1 + v.y, e3 = e2 + v.z;
    if (i + 0 < n) { rowptr[i+0] = e0; cursor[i+0] = e0; dinv[i+0] = rsqrtf((float)(v.x + 1)); }
    if (i + 1 < n) { rowptr[i+1] = e1; cursor[i+1] = e1; dinv[i+1] = rsqrtf((float)(v.y + 1)); }
    if (i + 2 < n) { rowptr[i+2] = e2; cursor[i+2] = e2; dinv[i+2] = rsqrtf((float)(v.z + 1)); }
    if (i + 3 < n) { rowptr[i+3] = e3; cursor[i+3] = e3; dinv[i+3] = rsqrtf((float)(v.w + 1)); }
}

// --- scatter edges into CSR slots ------------------------------------------
__global__ void scatter_kernel(const void* __restrict__ ei, const int* __restrict__ modep,
                               int* __restrict__ cursor, int* __restrict__ edge_src, int E) {
    int e = blockIdx.x * blockDim.x + threadIdx.x;
    if (e >= E) return;
    int mode = *modep;
    int r = load_idx(ei, (size_t)e, mode);
    int c = load_idx(ei, (size_t)E + e, mode);
    int pos = atomicAdd(&cursor[c], 1);
    edge_src[pos] = r;
}

// --- GEMM1: h = x @ W1   (K=25, W1 staged in LDS) --------------------------
__global__ __launch_bounds__(256) void gemm1_kernel(const float* __restrict__ x,
                                                    const float* __restrict__ W,
                                                    float* __restrict__ h, int n) {
    __shared__ float lw[25 * HID];
    for (int i = threadIdx.x; i < 25 * HID; i += 256) lw[i] = W[i];
    __syncthreads();
    int g = threadIdx.x >> 7, c = threadIdx.x & 127;
    for (int r = blockIdx.x * 2 + g; r < n; r += gridDim.x * 2) {
        const float* xr = x + (size_t)r * 25;
        float acc = 0.f;
        #pragma unroll
        for (int k = 0; k < 25; ++k) acc = fmaf(xr[k], lw[k * HID + c], acc);
        h[(size_t)r * HID + c] = acc;
    }
}

// --- propagation: out[c] = relu(dinv[c]*(sum_e h[src]*dinv[src] + h[c]*dinv[c]) + b)
// one wave per target node; lane owns 2 features (float2).
__global__ __launch_bounds__(256) void propagate_kernel(
    const float* __restrict__ h, const int* __restrict__ rowptr,
    const int* __restrict__ edge_src, const float* __restrict__ dinv,
    const float* __restrict__ bias, float* __restrict__ out, int n) {
    int wid = (blockIdx.x * 256 + threadIdx.x) >> 6;
    if (wid >= n) return;
    int lane = threadIdx.x & 63;
    int beg = rowptr[wid], end = rowptr[wid + 1];
    float dc = dinv[wid];
    float ax = 0.f, ay = 0.f;
    for (int b = beg; b < end; b += 64) {
        int m = end - b; if (m > 64) m = 64;
        int s = 0; float w = 0.f;
        if (lane < m) { s = edge_src[b + lane]; w = dinv[s]; }
        for (int j = 0; j < m; ++j) {
            int sj = __shfl(s, j);
            float wj = __shfl(w, j);
            float2 v = *(const float2*)(h + (size_t)sj * HID + lane * 2);
            ax = fmaf(v.x, wj, ax);
            ay = fmaf(v.y, wj, ay);
        }
    }
    {   // self loop
        float2 v = *(const float2*)(h + (size_t)wid * HID + lane * 2);
        ax = fmaf(v.x, dc, ax);
        ay = fmaf(v.y, dc, ay);
    }
    float bx = bias[lane * 2], by = bias[lane * 2 + 1];
    ax = fmaxf(fmaf(ax, dc, bx), 0.f);
    ay = fmaxf(fmaf(ay, dc, by), 0.f);
    *(float2*)(out + (size_t)wid * HID + lane * 2) = make_float2(ax, ay);
}

// --- BN stats: per-channel sum and sumsq -----------------------------------
__global__ __launch_bounds__(256) void bn_stats_kernel(const float* __restrict__ y,
                                                       float* __restrict__ sum,
                                                       float* __restrict__ sumsq, int n) {
    int c = threadIdx.x & 127;
    int g = threadIdx.x >> 7;
    float s = 0.f, s2 = 0.f;
    for (int r = blockIdx.x * 2 + g; r < n; r += gridDim.x * 2) {
        float v = y[(size_t)r * HID + c];
        s += v;
        s2 = fmaf(v, v, s2);
    }
    __shared__ float ls[256], ls2[256];
    ls[threadIdx.x] = s; ls2[threadIdx.x] = s2;
    __syncthreads();
    if (threadIdx.x < 128) {
        atomicAdd(&sum[c], ls[threadIdx.x] + ls[threadIdx.x + 128]);
        atomicAdd(&sumsq[c], ls2[threadIdx.x] + ls2[threadIdx.x + 128]);
    }
}

__global__ void bn_finalize_kernel(const float* __restrict__ sum, const float* __restrict__ sumsq,
                                   const float* __restrict__ gamma, const float* __restrict__ beta,
                                   float* __restrict__ scale, float* __restrict__ shift, float inv_n) {
    int c = threadIdx.x;
    float mean = sum[c] * inv_n;
    float var = sumsq[c] * inv_n - mean * mean;
    float sc = gamma[c] * rsqrtf(var + 1e-5f);
    scale[c] = sc;
    shift[c] = beta[c] - mean * sc;
}

// --- GEMM2: h2 = bn(y1) @ W2  (K=128), BN fused into tile load -------------
// 64-row x 128-col tile, K-chunks of 32; per-thread 8x4 register tile.
__global__ __launch_bounds__(256) void gemm2_kernel(
    const float* __restrict__ y, const float* __restrict__ W,
    const float* __restrict__ scale, const float* __restrict__ shift,
    float* __restrict__ out, int n) {
    __shared__ float lw[32][HID];   // [k][c]
    __shared__ float ly[32][68];    // [k][r] (64 rows + pad; 68*4 is 16B-aligned)
    int t = threadIdx.x;
    int base = blockIdx.x * 64;
    int c4 = (t & 31) * 4;
    int rg = t >> 5;  // 0..7
    float acc[8][4];
    #pragma unroll
    for (int r = 0; r < 8; ++r)
        #pragma unroll
        for (int c = 0; c < 4; ++c) acc[r][c] = 0.f;
    for (int kc = 0; kc < 4; ++kc) {
        #pragma unroll
        for (int i = 0; i < 16; ++i) {
            int idx = t + i * 256;
            int kk = idx >> 7, cc = idx & 127;
            lw[kk][cc] = W[(size_t)(kc * 32 + kk) * HID + cc];
        }
        #pragma unroll
        for (int i = 0; i < 8; ++i) {
            int idx = t + i * 256;
            int k = idx & 31, r = idx >> 5;
            int gr = base + r;
            int gk = kc * 32 + k;
            float v = 0.f;
            if (gr < n) v = fmaf(y[(size_t)gr * HID + gk], scale[gk], shift[gk]);
            ly[k][r] = v;
        }
        __syncthreads();
        #pragma unroll
        for (int k = 0; k < 32; ++k) {
            float4 wv = *(const float4*)&lw[k][c4];
            float4 y0 = *(const float4*)&ly[k][rg * 8];
            float4 y1 = *(const float4*)&ly[k][rg * 8 + 4];
            float yv[8] = {y0.x, y0.y, y0.z, y0.w, y1.x, y1.y, y1.z, y1.w};
            #pragma unroll
            for (int r = 0; r < 8; ++r) {
                acc[r][0] = fmaf(yv[r], wv.x, acc[r][0]);
                acc[r][1] = fmaf(yv[r], wv.y, acc[r][1]);
                acc[r][2] = fmaf(yv[r], wv.z, acc[r][2]);
                acc[r][3] = fmaf(yv[r], wv.w, acc[r][3]);
            }
        }
        __syncthreads();
    }
    #pragma unroll
    for (int r = 0; r < 8; ++r) {
        int gr = base + rg * 8 + r;
        if (gr < n)
            *(float4*)&out[(size_t)gr * HID + c4] =
                make_float4(acc[r][0], acc[r][1], acc[r][2], acc[r][3]);
    }
}

extern "C" void kernel_launch(void* const* d_in, const int* in_sizes, int n_in,
                              void* d_out, int out_size, void* d_ws, size_t ws_size,
                              hipStream_t stream) {
    const float* x     = (const float*)d_in[0];
    const void*  ei    = d_in[1];
    const float* W1    = (const float*)d_in[2];
    const float* b1    = (const float*)d_in[3];
    const float* gamma = (const float*)d_in[4];
    const float* beta  = (const float*)d_in[5];
    const float* W2    = (const float*)d_in[6];
    const float* b2    = (const float*)d_in[7];
    float* out = (float*)d_out;

    const int f_in = 25;
    int n = in_sizes[0] / f_in;
    int E = in_sizes[1] / 2;
    int nb = (n + SCAN_CHUNK - 1) / SCAN_CHUNK;

    char* ws = (char*)d_ws;
    size_t off = 0;
    auto alloc = [&](size_t bytes) -> void* {
        void* p = ws + off;
        off += (bytes + 511) & ~(size_t)511;
        return p;
    };
    int*   cnt      = (int*)alloc((size_t)n * 4);
    int*   rowptr   = (int*)alloc(((size_t)n + 1) * 4);
    int*   cursor   = (int*)alloc((size_t)n * 4);
    float* dinv     = (float*)alloc((size_t)n * 4);
    int*   edge_src = (int*)alloc((size_t)E * 4);
    float* bnacc    = (float*)alloc(256 * 4);   // sum[128] ++ sumsq[128]
    float* sclshift = (float*)alloc(256 * 4);   // scale[128] ++ shift[128]
    int*   mode     = (int*)alloc(4);
    int*   blocksum = (int*)alloc((size_t)nb * 4);
    int*   blockoff = (int*)alloc((size_t)nb * 4);
    float* h        = (float*)alloc((size_t)n * HID * 4);  // h1, then h2

    hipMemsetAsync(cnt, 0, (size_t)n * 4, stream);
    hipMemsetAsync(bnacc, 0, 256 * 4, stream);

    detect_kernel<<<1, 256, 0, stream>>>((const unsigned int*)ei, mode, 2 * E);
    count_kernel<<<(E + 255) / 256, 256, 0, stream>>>(ei, mode, cnt, E);
    scan_partial_kernel<<<nb, 256, 0, stream>>>(cnt, blocksum, n);
    scan_blocksums_kernel<<<1, 1024, 0, stream>>>(blocksum, blockoff, rowptr, nb, n);
    scan_finalize_kernel<<<nb, 256, 0, stream>>>(cnt, blockoff, rowptr, cursor, dinv, n);
    scatter_kernel<<<(E + 255) / 256, 256, 0, stream>>>(ei, mode, cursor, edge_src, E);

    // layer 1: h1 = x@W1 ; y1 = relu(prop(h1) + b1) -> stored in d_out
    gemm1_kernel<<<4096, 256, 0, stream>>>(x, W1, h, n);
    propagate_kernel<<<(n + 3) / 4, 256, 0, stream>>>(h, rowptr, edge_src, dinv, b1, out, n);

    // batchnorm stats on y1
    bn_stats_kernel<<<512, 256, 0, stream>>>(out, bnacc, bnacc + 128, n);
    bn_finalize_kernel<<<1, 128, 0, stream>>>(bnacc, bnacc + 128, gamma, beta,
                                              sclshift, sclshift + 128, 1.0f / (float)n);

    // layer 2: h2 = bn(y1)@W2 (into h buffer) ; out = relu(prop(h2) + b2)
    gemm2_kernel<<<(n + 63) / 64, 256, 0, stream>>>(out, W2, sclshift, sclshift + 128, h, n);
    propagate_kernel<<<(n + 3) / 4, 256, 0, stream>>>(h, rowptr, edge_src, dinv, b2, out, n);
}

// Round 6
// 592.832 us; speedup vs baseline: 1.5972x; 1.1485x over previous
//
#include <hip/hip_runtime.h>
#include <stdint.h>

// ---------------------------------------------------------------------------
// 2-layer GCN: relu(gcn(x,W1,b1)) -> batchnorm -> relu(gcn(.,W2,b2))
// n=100000, E=1.6M, f_in=25, hid=128.
// R2: parallel scan (947 -> 681 us, matched prediction).
// R6: (a) gemm2 rebuilt: 128x128 tile, 8x8 per-thread regs (FMA:LDS ratio 2x,
//     conflict-free ly staging via 132-float row stride + float4-along-K);
//     was 24 TF / 15% of fp32 peak at 137 us.
//     (b) intermediate h buffers bf16 (halves propagate gather + gemm writes);
//     y1 and final output stay fp32; accumulation all fp32.
// ---------------------------------------------------------------------------

#define HID 128
#define SCAN_CHUNK 1024   // elements per block in the parallel scan

__device__ __forceinline__ unsigned short f2bf(float f) {
    unsigned int u = __float_as_uint(f);
    unsigned int r = (u + 0x7FFFu + ((u >> 16) & 1u)) >> 16;  // RNE
    return (unsigned short)r;
}
__device__ __forceinline__ unsigned int pack2bf(float lo, float hi) {
    return (unsigned int)f2bf(lo) | ((unsigned int)f2bf(hi) << 16);
}

// --- detect whether edge_index buffer is int64 or int32 --------------------
// int64 little-endian values < 2^31: every odd 32-bit word is 0.
__global__ void detect_kernel(const unsigned int* __restrict__ w, int* __restrict__ mode, int nwords) {
    __shared__ int any;
    if (threadIdx.x == 0) any = 0;
    __syncthreads();
    for (int i = threadIdx.x * 2 + 1; i < nwords && i < 8192; i += 512) {
        if (w[i] != 0) atomicOr(&any, 1);
    }
    __syncthreads();
    if (threadIdx.x == 0) *mode = any ? 0 : 1;  // 1 => int64 layout
}

__device__ __forceinline__ int load_idx(const void* ei, size_t i, int mode) {
    return mode ? (int)((const long long*)ei)[i] : ((const int*)ei)[i];
}

// --- in-degree histogram (targets = col) -----------------------------------
__global__ void count_kernel(const void* __restrict__ ei, const int* __restrict__ modep,
                             int* __restrict__ cnt, int E) {
    int e = blockIdx.x * blockDim.x + threadIdx.x;
    if (e >= E) return;
    int mode = *modep;
    int c = load_idx(ei, (size_t)E + e, mode);
    atomicAdd(&cnt[c], 1);
}

// --- parallel scan phase 1: per-block sums ---------------------------------
__global__ __launch_bounds__(256) void scan_partial_kernel(const int* __restrict__ cnt,
                                                           int* __restrict__ blocksum, int n) {
    int i = blockIdx.x * SCAN_CHUNK + threadIdx.x * 4;
    int4 v = make_int4(0, 0, 0, 0);
    if (i + 3 < n) v = *(const int4*)(cnt + i);
    else {
        if (i + 0 < n) v.x = cnt[i + 0];
        if (i + 1 < n) v.y = cnt[i + 1];
        if (i + 2 < n) v.z = cnt[i + 2];
    }
    int s = v.x + v.y + v.z + v.w;
    #pragma unroll
    for (int off = 32; off > 0; off >>= 1) s += __shfl_down(s, off);
    __shared__ int ls[4];
    if ((threadIdx.x & 63) == 0) ls[threadIdx.x >> 6] = s;
    __syncthreads();
    if (threadIdx.x == 0) blocksum[blockIdx.x] = ls[0] + ls[1] + ls[2] + ls[3];
}

// --- parallel scan phase 2: scan block sums (nb <= 1024) -------------------
__global__ __launch_bounds__(1024) void scan_blocksums_kernel(const int* __restrict__ blocksum,
                                                              int* __restrict__ blockoff,
                                                              int* __restrict__ rowptr,
                                                              int nb, int n) {
    __shared__ int s[1024];
    int t = threadIdx.x;
    int own = (t < nb) ? blocksum[t] : 0;
    s[t] = own;
    __syncthreads();
    for (int off = 1; off < 1024; off <<= 1) {
        int v = s[t] + ((t >= off) ? s[t - off] : 0);
        __syncthreads();
        s[t] = v;
        __syncthreads();
    }
    if (t < nb) blockoff[t] = s[t] - own;  // exclusive
    if (t == 1023) rowptr[n] = s[1023];    // total
}

// --- parallel scan phase 3: per-element exclusive prefix + dinv ------------
__global__ __launch_bounds__(256) void scan_finalize_kernel(const int* __restrict__ cnt,
                                                            const int* __restrict__ blockoff,
                                                            int* __restrict__ rowptr,
                                                            int* __restrict__ cursor,
                                                            float* __restrict__ dinv, int n) {
    int t = threadIdx.x;
    int i = blockIdx.x * SCAN_CHUNK + t * 4;
    int4 v = make_int4(0, 0, 0, 0);
    if (i + 3 < n) v = *(const int4*)(cnt + i);
    else {
        if (i + 0 < n) v.x = cnt[i + 0];
        if (i + 1 < n) v.y = cnt[i + 1];
        if (i + 2 < n) v.z = cnt[i + 2];
    }
    int own = v.x + v.y + v.z + v.w;
    __shared__ int s[256];
    s[t] = own;
    __syncthreads();
    for (int off = 1; off < 256; off <<= 1) {
        int x = s[t] + ((t >= off) ? s[t - off] : 0);
        __syncthreads();
        s[t] = x;
        __syncthreads();
    }
    int e0 = blockoff[blockIdx.x] + s[t] - own;  // exclusive prefix of element i
    int e1 = e0 + v.x, e2 = e1 + v.y, e3 = e2 + v.z;
    if (i + 0 < n) { rowptr[i+0] = e0; cursor[i+0] = e0; dinv[i+0] = rsqrtf((float)(v.x + 1)); }
    if (i + 1 < n) { rowptr[i+1] = e1; cursor[i+1] = e1; dinv[i+1] = rsqrtf((float)(v.y + 1)); }
    if (i + 2 < n) { rowptr[i+2] = e2; cursor[i+2] = e2; dinv[i+2] = rsqrtf((float)(v.z + 1)); }
    if (i + 3 < n) { rowptr[i+3] = e3; cursor[i+3] = e3; dinv[i+3] = rsqrtf((float)(v.w + 1)); }
}

// --- scatter edges into CSR slots ------------------------------------------
__global__ void scatter_kernel(const void* __restrict__ ei, const int* __restrict__ modep,
                               int* __restrict__ cursor, int* __restrict__ edge_src, int E) {
    int e = blockIdx.x * blockDim.x + threadIdx.x;
    if (e >= E) return;
    int mode = *modep;
    int r = load_idx(ei, (size_t)e, mode);
    int c = load_idx(ei, (size_t)E + e, mode);
    int pos = atomicAdd(&cursor[c], 1);
    edge_src[pos] = r;
}

// --- GEMM1: h = bf16(x @ W1)   (K=25, W1 staged in LDS) --------------------
__global__ __launch_bounds__(256) void gemm1_kernel(const float* __restrict__ x,
                                                    const float* __restrict__ W,
                                                    unsigned short* __restrict__ h, int n) {
    __shared__ float lw[25 * HID];
    for (int i = threadIdx.x; i < 25 * HID; i += 256) lw[i] = W[i];
    __syncthreads();
    int g = threadIdx.x >> 7, c = threadIdx.x & 127;
    for (int r = blockIdx.x * 2 + g; r < n; r += gridDim.x * 2) {
        const float* xr = x + (size_t)r * 25;
        float acc = 0.f;
        #pragma unroll
        for (int k = 0; k < 25; ++k) acc = fmaf(xr[k], lw[k * HID + c], acc);
        h[(size_t)r * HID + c] = f2bf(acc);
    }
}

// --- propagation: out[c] = relu(dinv[c]*(sum_e h[src]*dinv[src] + h[c]*dinv[c]) + b)
// h is bf16 (read as packed uint per lane: 2 feats); accumulate fp32; out fp32.
__global__ __launch_bounds__(256) void propagate_kernel(
    const unsigned short* __restrict__ h, const int* __restrict__ rowptr,
    const int* __restrict__ edge_src, const float* __restrict__ dinv,
    const float* __restrict__ bias, float* __restrict__ out, int n) {
    int wid = (blockIdx.x * 256 + threadIdx.x) >> 6;
    if (wid >= n) return;
    int lane = threadIdx.x & 63;
    int beg = rowptr[wid], end = rowptr[wid + 1];
    float dc = dinv[wid];
    float ax = 0.f, ay = 0.f;
    const unsigned int* hp = (const unsigned int*)h;  // 64 uints per row
    for (int b = beg; b < end; b += 64) {
        int m = end - b; if (m > 64) m = 64;
        int s = 0; float w = 0.f;
        if (lane < m) { s = edge_src[b + lane]; w = dinv[s]; }
        for (int j = 0; j < m; ++j) {
            int sj = __shfl(s, j);
            float wj = __shfl(w, j);
            unsigned int v = hp[(size_t)sj * 64 + lane];
            ax = fmaf(__uint_as_float(v << 16), wj, ax);
            ay = fmaf(__uint_as_float(v & 0xffff0000u), wj, ay);
        }
    }
    {   // self loop
        unsigned int v = hp[(size_t)wid * 64 + lane];
        ax = fmaf(__uint_as_float(v << 16), dc, ax);
        ay = fmaf(__uint_as_float(v & 0xffff0000u), dc, ay);
    }
    float bx = bias[lane * 2], by = bias[lane * 2 + 1];
    ax = fmaxf(fmaf(ax, dc, bx), 0.f);
    ay = fmaxf(fmaf(ay, dc, by), 0.f);
    *(float2*)(out + (size_t)wid * HID + lane * 2) = make_float2(ax, ay);
}

// --- BN stats: per-channel sum and sumsq -----------------------------------
__global__ __launch_bounds__(256) void bn_stats_kernel(const float* __restrict__ y,
                                                       float* __restrict__ sum,
                                                       float* __restrict__ sumsq, int n) {
    int c = threadIdx.x & 127;
    int g = threadIdx.x >> 7;
    float s = 0.f, s2 = 0.f;
    for (int r = blockIdx.x * 2 + g; r < n; r += gridDim.x * 2) {
        float v = y[(size_t)r * HID + c];
        s += v;
        s2 = fmaf(v, v, s2);
    }
    __shared__ float ls[256], ls2[256];
    ls[threadIdx.x] = s; ls2[threadIdx.x] = s2;
    __syncthreads();
    if (threadIdx.x < 128) {
        atomicAdd(&sum[c], ls[threadIdx.x] + ls[threadIdx.x + 128]);
        atomicAdd(&sumsq[c], ls2[threadIdx.x] + ls2[threadIdx.x + 128]);
    }
}

__global__ void bn_finalize_kernel(const float* __restrict__ sum, const float* __restrict__ sumsq,
                                   const float* __restrict__ gamma, const float* __restrict__ beta,
                                   float* __restrict__ scale, float* __restrict__ shift, float inv_n) {
    int c = threadIdx.x;
    float mean = sum[c] * inv_n;
    float var = sumsq[c] * inv_n - mean * mean;
    float sc = gamma[c] * rsqrtf(var + 1e-5f);
    scale[c] = sc;
    shift[c] = beta[c] - mean * sc;
}

// --- GEMM2: h2 = bf16(bn(y1) @ W2)  (K=128), BN fused into tile load -------
// 128-row x 128-col tile, K-chunks of 32; per-thread 8x8 register tile.
// ly row stride 132 floats: float4 reads 16B-aligned (528B rows) and staging
// b32 stores hit distinct banks (bank = r mod 32 across lanes).
__global__ __launch_bounds__(256) void gemm2_kernel(
    const float* __restrict__ y, const float* __restrict__ W,
    const float* __restrict__ scale, const float* __restrict__ shift,
    unsigned short* __restrict__ out, int n) {
    __shared__ float lw[32][HID];       // [k][c] 16KB
    __shared__ float ly[32][132];       // [k][r] 16.5KB (pad: align + bank-free)
    int t = threadIdx.x;
    int base = blockIdx.x * 128;
    int c8 = (t & 15) * 8;   // col start (16 groups x 8 cols)
    int rg = t >> 4;         // 0..15, rows rg*8 .. rg*8+7
    float acc[8][8];
    #pragma unroll
    for (int r = 0; r < 8; ++r)
        #pragma unroll
        for (int c = 0; c < 8; ++c) acc[r][c] = 0.f;

    int sr = t & 127;        // staging row
    int sg = t >> 7;         // 0/1: which half of k
    for (int kc = 0; kc < 4; ++kc) {
        // stage W2 chunk: 32x128, coalesced b32 (conflict-free)
        #pragma unroll
        for (int i = 0; i < 16; ++i) {
            int idx = t + i * 256;
            int kk = idx >> 7, cc = idx & 127;
            lw[kk][cc] = W[(size_t)(kc * 32 + kk) * HID + cc];
        }
        // stage y chunk: 128 rows x 32 k, float4 along K + BN fused
        int gr = base + sr;
        #pragma unroll
        for (int i = 0; i < 4; ++i) {
            int k0 = (sg * 4 + i) * 4;
            float4 vy = make_float4(0.f, 0.f, 0.f, 0.f);
            if (gr < n) vy = *(const float4*)(y + (size_t)gr * HID + kc * 32 + k0);
            int gk = kc * 32 + k0;
            ly[k0 + 0][sr] = fmaf(vy.x, scale[gk + 0], shift[gk + 0]);
            ly[k0 + 1][sr] = fmaf(vy.y, scale[gk + 1], shift[gk + 1]);
            ly[k0 + 2][sr] = fmaf(vy.z, scale[gk + 2], shift[gk + 2]);
            ly[k0 + 3][sr] = fmaf(vy.w, scale[gk + 3], shift[gk + 3]);
        }
        __syncthreads();
        #pragma unroll
        for (int k = 0; k < 32; ++k) {
            float4 w0 = *(const float4*)&lw[k][c8];
            float4 w1 = *(const float4*)&lw[k][c8 + 4];
            float4 ya = *(const float4*)&ly[k][rg * 8];
            float4 yb = *(const float4*)&ly[k][rg * 8 + 4];
            float yv[8] = {ya.x, ya.y, ya.z, ya.w, yb.x, yb.y, yb.z, yb.w};
            float wv[8] = {w0.x, w0.y, w0.z, w0.w, w1.x, w1.y, w1.z, w1.w};
            #pragma unroll
            for (int r = 0; r < 8; ++r)
                #pragma unroll
                for (int c = 0; c < 8; ++c)
                    acc[r][c] = fmaf(yv[r], wv[c], acc[r][c]);
        }
        __syncthreads();
    }
    #pragma unroll
    for (int r = 0; r < 8; ++r) {
        int gr = base + rg * 8 + r;
        if (gr < n) {
            uint4 p;
            p.x = pack2bf(acc[r][0], acc[r][1]);
            p.y = pack2bf(acc[r][2], acc[r][3]);
            p.z = pack2bf(acc[r][4], acc[r][5]);
            p.w = pack2bf(acc[r][6], acc[r][7]);
            *(uint4*)&out[(size_t)gr * HID + c8] = p;
        }
    }
}

extern "C" void kernel_launch(void* const* d_in, const int* in_sizes, int n_in,
                              void* d_out, int out_size, void* d_ws, size_t ws_size,
                              hipStream_t stream) {
    const float* x     = (const float*)d_in[0];
    const void*  ei    = d_in[1];
    const float* W1    = (const float*)d_in[2];
    const float* b1    = (const float*)d_in[3];
    const float* gamma = (const float*)d_in[4];
    const float* beta  = (const float*)d_in[5];
    const float* W2    = (const float*)d_in[6];
    const float* b2    = (const float*)d_in[7];
    float* out = (float*)d_out;

    const int f_in = 25;
    int n = in_sizes[0] / f_in;
    int E = in_sizes[1] / 2;
    int nb = (n + SCAN_CHUNK - 1) / SCAN_CHUNK;

    char* ws = (char*)d_ws;
    size_t off = 0;
    auto alloc = [&](size_t bytes) -> void* {
        void* p = ws + off;
        off += (bytes + 511) & ~(size_t)511;
        return p;
    };
    int*   cnt      = (int*)alloc((size_t)n * 4);
    int*   rowptr   = (int*)alloc(((size_t)n + 1) * 4);
    int*   cursor   = (int*)alloc((size_t)n * 4);
    float* dinv     = (float*)alloc((size_t)n * 4);
    int*   edge_src = (int*)alloc((size_t)E * 4);
    float* bnacc    = (float*)alloc(256 * 4);   // sum[128] ++ sumsq[128]
    float* sclshift = (float*)alloc(256 * 4);   // scale[128] ++ shift[128]
    int*   mode     = (int*)alloc(4);
    int*   blocksum = (int*)alloc((size_t)nb * 4);
    int*   blockoff = (int*)alloc((size_t)nb * 4);
    unsigned short* h = (unsigned short*)alloc((size_t)n * HID * 2);  // bf16 h1, then h2

    hipMemsetAsync(cnt, 0, (size_t)n * 4, stream);
    hipMemsetAsync(bnacc, 0, 256 * 4, stream);

    detect_kernel<<<1, 256, 0, stream>>>((const unsigned int*)ei, mode, 2 * E);
    count_kernel<<<(E + 255) / 256, 256, 0, stream>>>(ei, mode, cnt, E);
    scan_partial_kernel<<<nb, 256, 0, stream>>>(cnt, blocksum, n);
    scan_blocksums_kernel<<<1, 1024, 0, stream>>>(blocksum, blockoff, rowptr, nb, n);
    scan_finalize_kernel<<<nb, 256, 0, stream>>>(cnt, blockoff, rowptr, cursor, dinv, n);
    scatter_kernel<<<(E + 255) / 256, 256, 0, stream>>>(ei, mode, cursor, edge_src, E);

    // layer 1: h1 = bf16(x@W1) ; y1 = relu(prop(h1) + b1) -> stored in d_out (fp32)
    gemm1_kernel<<<4096, 256, 0, stream>>>(x, W1, h, n);
    propagate_kernel<<<(n + 3) / 4, 256, 0, stream>>>(h, rowptr, edge_src, dinv, b1, out, n);

    // batchnorm stats on y1
    bn_stats_kernel<<<512, 256, 0, stream>>>(out, bnacc, bnacc + 128, n);
    bn_finalize_kernel<<<1, 128, 0, stream>>>(bnacc, bnacc + 128, gamma, beta,
                                              sclshift, sclshift + 128, 1.0f / (float)n);

    // layer 2: h2 = bf16(bn(y1)@W2) ; out = relu(prop(h2) + b2)
    gemm2_kernel<<<(n + 127) / 128, 256, 0, stream>>>(out, W2, sclshift, sclshift + 128, h, n);
    propagate_kernel<<<(n + 3) / 4, 256, 0, stream>>>(h, rowptr, edge_src, dinv, b2, out, n);
}